// Round 21
// baseline (5039.679 us; speedup 1.0000x reference)
//
#include <hip/hip_runtime.h>
#include <math.h>

#define T_STEPS 512
#define BATCH   16
#define DIM     1024
#define M_TOTAL (T_STEPS*BATCH)              // 8192
#define OUT_SEC ((size_t)M_TOTAL*DIM)        // 8388608 floats (output section)
#define BD      (BATCH*DIM)

// ws: two tagged ping-pong exchanges (8B packets, 2 slots x 16 batches x 1024)
//   fast @ 0        : workgroup-scope stores (local-XCD L2, write-through L1)
//   auth @ 2*BD u2  : sc0 sc1 stores (LLC, verified r17 protocol)
#define TAG_UNITS   ((size_t)2*BD)
#define AUTH_BYTES  (TAG_UNITS*8)            // 256 KB (fallback minimum)
#define DUAL_BYTES  (TAG_UNITS*8*2)          // 512 KB

// prep grid: 512 GEMM blocks (128x128 tile) + 2048 gate blocks
#define NB_GEMM 512
#define NB_GATE 2048

// ---------------------------------------------------------------------------
__device__ __forceinline__ float wred64(float v){
  #pragma unroll
  for (int off = 32; off >= 1; off >>= 1) v += __shfl_xor(v, off, 64);
  return v;
}

#define KA(v) asm volatile("" : "+v"(v.x), "+v"(v.y), "+v"(v.z), "+v"(v.w))

// ---------------------------------------------------------------------------
// Prep: blocks [0,512) = pre GEMM 128x128 tile, double-buffered staging,
// CONSECUTIVE 8x8 fragments -> ds_read_b128 LDS reads (af broadcast
// conflict-free, bf 4-way) => compute-bound. blocks [512,2560) = gate.
__global__ __launch_bounds__(256) void prep_kernel(const float* __restrict__ X,
                                                   const float* __restrict__ Wx,
                                                   const float* __restrict__ bias,
                                                   float* __restrict__ out_h,
                                                   const float* __restrict__ z,
                                                   float* __restrict__ gate_out){
  __shared__ __align__(16) float As[8][128];   // k-major A tile (4 KB)
  __shared__ __align__(16) float Bs[8][128];   // k-major B tile (4 KB)
  const int tid = threadIdx.x;

  if (blockIdx.x < NB_GEMM){
    const int bm = blockIdx.x >> 3;
    const int bn = blockIdx.x & 7;
    const int m0 = bm*128, n0 = bn*128;
    const int tx = tid & 15, ty = tid >> 4;   // 16x16 thread grid
    const int sm = tid >> 1;                  // staging row 0..127
    const int sk = (tid & 1) * 4;             // staging k offset {0,4}

    float acc[8][8] = {};

    const float* Xp = X  + (size_t)(m0+sm)*DIM + sk;
    const float* Wp = Wx + (size_t)(n0+sm)*DIM + sk;

    float4 av = *reinterpret_cast<const float4*>(Xp);
    float4 wv = *reinterpret_cast<const float4*>(Wp);

    for (int k0 = 0; k0 < DIM; k0 += 8){
      __syncthreads();                  // previous compute done reading LDS
      As[sk+0][sm]=av.x; As[sk+1][sm]=av.y; As[sk+2][sm]=av.z; As[sk+3][sm]=av.w;
      Bs[sk+0][sm]=wv.x; Bs[sk+1][sm]=wv.y; Bs[sk+2][sm]=wv.z; Bs[sk+3][sm]=wv.w;
      const int kn = (k0 + 8 < DIM) ? (k0 + 8) : 0;
      const float4 av2 = *reinterpret_cast<const float4*>(Xp + kn);
      const float4 wv2 = *reinterpret_cast<const float4*>(Wp + kn);
      __syncthreads();
      #pragma unroll
      for (int k = 0; k < 8; ++k){
        const float4 a0 = *reinterpret_cast<const float4*>(&As[k][ty*8]);
        const float4 a1 = *reinterpret_cast<const float4*>(&As[k][ty*8+4]);
        const float4 b0 = *reinterpret_cast<const float4*>(&Bs[k][tx*8]);
        const float4 b1 = *reinterpret_cast<const float4*>(&Bs[k][tx*8+4]);
        const float af[8] = {a0.x,a0.y,a0.z,a0.w,a1.x,a1.y,a1.z,a1.w};
        const float bf[8] = {b0.x,b0.y,b0.z,b0.w,b1.x,b1.y,b1.z,b1.w};
        #pragma unroll
        for (int i = 0; i < 8; ++i)
          #pragma unroll
          for (int j = 0; j < 8; ++j) acc[i][j] = fmaf(af[i], bf[j], acc[i][j]);
      }
      av = av2; wv = wv2;
    }

    const float4 bv0 = *reinterpret_cast<const float4*>(bias + n0 + tx*8);
    const float4 bv1 = *reinterpret_cast<const float4*>(bias + n0 + tx*8 + 4);
    #pragma unroll
    for (int i = 0; i < 8; ++i){
      // pre row m -> h slot m+BATCH (pre[t] lives where h[t+1] goes)
      float* dst = out_h + (size_t)(m0 + ty*8 + i + BATCH)*DIM + n0 + tx*8;
      float4 o0; o0.x=acc[i][0]+bv0.x; o0.y=acc[i][1]+bv0.y;
                 o0.z=acc[i][2]+bv0.z; o0.w=acc[i][3]+bv0.w;
      float4 o1; o1.x=acc[i][4]+bv1.x; o1.y=acc[i][5]+bv1.y;
                 o1.z=acc[i][6]+bv1.z; o1.w=acc[i][7]+bv1.w;
      *reinterpret_cast<float4*>(dst)     = o0;
      *reinterpret_cast<float4*>(dst + 4) = o1;
    }
  } else {
    const int gb   = blockIdx.x - NB_GEMM;
    const int row  = gb * 4 + (tid >> 6);
    const int lane = tid & 63;
    const float* zr = z + (size_t)row * DIM;

    float x[16];
    #pragma unroll
    for (int e = 0; e < 4; ++e){
      float4 v = *reinterpret_cast<const float4*>(zr + e*256 + lane*4);
      x[e*4+0]=v.x; x[e*4+1]=v.y; x[e*4+2]=v.z; x[e*4+3]=v.w;
    }

    float m = x[0];
    #pragma unroll
    for (int i = 1; i < 16; ++i) m = fmaxf(m, x[i]);
    #pragma unroll
    for (int off = 32; off >= 1; off >>= 1) m = fmaxf(m, __shfl_xor(m, off, 64));

    float lo = m - 1.0f, hi = m;
    for (int it = 0; it < 30; ++it){
      float mid = 0.5f*(lo + hi);
      float f = 0.f;
      #pragma unroll
      for (int i = 0; i < 16; ++i) f += fmaxf(x[i] - mid, 0.f);
      f = wred64(f);
      if (f >= 1.0f) lo = mid; else hi = mid;
    }
    float s = 0.f, kc = 0.f;
    #pragma unroll
    for (int i = 0; i < 16; ++i){ if (x[i] > lo){ s += x[i]; kc += 1.f; } }
    s = wred64(s); kc = wred64(kc);
    const float tau = (s - 1.0f) / kc;

    float p[16]; float ps = 0.f;
    #pragma unroll
    for (int i = 0; i < 16; ++i){ p[i] = sqrtf(fmaxf(x[i] - tau, 0.f)); ps += p[i]; }
    ps = wred64(ps);
    const float inv = 1.0f / (ps + 1e-10f);

    float* go = gate_out + (size_t)row * DIM;
    #pragma unroll
    for (int e = 0; e < 4; ++e){
      float4 v; v.x=p[e*4]*inv; v.y=p[e*4+1]*inv; v.z=p[e*4+2]*inv; v.w=p[e*4+3]*inv;
      *reinterpret_cast<float4*>(go + e*256 + lane*4) = v;
    }
  }
}

// ---------------------------------------------------------------------------
// Kernel C: r20 dual-path exchange with FAST-FIRST polling. r20's poll waited
// vmcnt(0) on BOTH the L2 and LLC loads every iteration -> cadence gated by
// LLC RTT even when L2 data was ready (FETCH collapsed but time didn't).
// Now: spin on the fast (local-XCD L2) copy alone (~L2 RTT cadence); after
// 64 failed spins fall into the r20-verified dual loop (cannot hang under
// any block->XCD placement). Same packet protocol, 8B-atomic, monotone tags.
template<bool DUAL>
__global__ __launch_bounds__(512, 1) void rnn_tag(const float* __restrict__ h0,
                                                  const float* __restrict__ Wh,
                                                  float* __restrict__ out,
                                                  uint2* __restrict__ fastbuf,
                                                  uint2* __restrict__ authbuf){
  float* out_h = out + OUT_SEC;
  const int tid  = threadIdx.x;
  const int lane = tid & 63;
  const int w    = tid >> 6;            // wave 0..7
  const int b    = blockIdx.x & 15;     // batch (XCD-affine under round-robin)
  const int s    = blockIdx.x >> 4;     // slice
  const int dbase = s*64 + w*8;

  __shared__ float hbuf[2][DIM];        // 8 KB ping-pong broadcast buffer

  // W_h slice: 8 rows x 16 cols = 32 float4
  float4 wreg[8][4];
  #pragma unroll
  for (int r = 0; r < 8; ++r)
    #pragma unroll
    for (int j = 0; j < 4; ++j)
      wreg[r][j] = *reinterpret_cast<const float4*>(
          Wh + (size_t)(dbase + r)*DIM + lane*4 + j*256);

  KA(wreg[0][0]); KA(wreg[0][1]); KA(wreg[0][2]); KA(wreg[0][3]);
  KA(wreg[1][0]); KA(wreg[1][1]); KA(wreg[1][2]); KA(wreg[1][3]);
  KA(wreg[2][0]); KA(wreg[2][1]); KA(wreg[2][2]); KA(wreg[2][3]);
  KA(wreg[3][0]); KA(wreg[3][1]); KA(wreg[3][2]); KA(wreg[3][3]);
  KA(wreg[4][0]); KA(wreg[4][1]); KA(wreg[4][2]); KA(wreg[4][3]);
  KA(wreg[5][0]); KA(wreg[5][1]); KA(wreg[5][2]); KA(wreg[5][3]);
  KA(wreg[6][0]); KA(wreg[6][1]); KA(wreg[6][2]); KA(wreg[6][3]);
  KA(wreg[7][0]); KA(wreg[7][1]); KA(wreg[7][2]); KA(wreg[7][3]);

  // h[0] = h0 in the validated h section (output slot 0)
  if (tid < 16)
    reinterpret_cast<float4*>(out_h + (size_t)b*DIM + s*64)[tid] =
        reinterpret_cast<const float4*>(h0 + (size_t)b*DIM + s*64)[tid];

  const int myrow   = lane >> 3;            // 0..7
  const bool active = ((lane & 7) == 0);    // 8 store lanes per wave

  for (int t = 0; t < T_STEPS; ++t){
    // prefetch pre (h slot t+1) and gate (out slot t) for this lane's row
    float pre_v = 0.f, gate_v = 0.f;
    if (active){
      const size_t d = dbase + myrow;
      pre_v  = out_h[(size_t)(t+1)*BD + (size_t)b*DIM + d];
      gate_v = out  [(size_t)t*BD     + (size_t)b*DIM + d];
    }

    // ---- acquire h[t][b] into LDS (distributed poll, 2 packets/thread) ----
    if (t == 0){
      const float2 hl = *reinterpret_cast<const float2*>(h0 + (size_t)b*DIM + 2*tid);
      *reinterpret_cast<float2*>(&hbuf[0][2*tid]) = hl;
    } else {
      const size_t off = (size_t)(t & 1)*BD + (size_t)b*DIM + 2*tid;
      const unsigned want = (unsigned)t;
      float2 hv2;
      if constexpr (DUAL){
        const uint2* pf = fastbuf + off;
        const uint2* pa = authbuf + off;
        int spin = 0;
        for (;;){
          float4 f;
          asm volatile("global_load_dwordx4 %0, %1, off sc0\n\t"
                       "s_waitcnt vmcnt(0)"
                       : "=&v"(f) : "v"(pf) : "memory");
          if (__float_as_uint(f.y) == want && __float_as_uint(f.w) == want){
            hv2 = make_float2(f.x, f.z); break;
          }
          if (++spin >= 64){
            // safety net: r20-verified dual loop (covers cross-XCD readers)
            float4 f2, a;
            for (;;){
              asm volatile("global_load_dwordx4 %0, %2, off sc0\n\t"
                           "global_load_dwordx4 %1, %3, off sc0 sc1\n\t"
                           "s_waitcnt vmcnt(0)"
                           : "=&v"(f2), "=&v"(a) : "v"(pf), "v"(pa) : "memory");
              const bool ok0 = (__float_as_uint(f2.y)==want) | (__float_as_uint(a.y)==want);
              const bool ok1 = (__float_as_uint(f2.w)==want) | (__float_as_uint(a.w)==want);
              if (ok0 & ok1) break;
            }
            hv2.x = (__float_as_uint(f2.y)==want) ? f2.x : a.x;
            hv2.y = (__float_as_uint(f2.w)==want) ? f2.z : a.z;
            break;
          }
        }
      } else {
        const uint2* pp = authbuf + off;
        float4 q;
        do {
          asm volatile("global_load_dwordx4 %0, %1, off sc0 sc1\n\t"
                       "s_waitcnt vmcnt(0)"
                       : "=&v"(q) : "v"(pp) : "memory");
        } while (__float_as_uint(q.y) != want || __float_as_uint(q.w) != want);
        hv2 = make_float2(q.x, q.z);
      }
      *reinterpret_cast<float2*>(&hbuf[t & 1][2*tid]) = hv2;
    }
    __syncthreads();

    const float* src = &hbuf[t & 1][0];
    const float4 hv0 = *reinterpret_cast<const float4*>(src + lane*4);
    const float4 hv1 = *reinterpret_cast<const float4*>(src + 256 + lane*4);
    const float4 hv2r = *reinterpret_cast<const float4*>(src + 512 + lane*4);
    const float4 hv3 = *reinterpret_cast<const float4*>(src + 768 + lane*4);

    // ---- partials: v[r] = dot(wreg[r], hv) over this lane's 16 cols ----
    float v0,v1,v2,v3,v4,v5,v6,v7;
    {
      #define DOTROW(R, OUTV)                                            \
        { const float4 w0=wreg[R][0], w1=wreg[R][1],                     \
                       w2=wreg[R][2], w3=wreg[R][3];                     \
          float a_ = 0.f;                                                \
          a_ = fmaf(w0.x,hv0.x,fmaf(w0.y,hv0.y,fmaf(w0.z,hv0.z,fmaf(w0.w,hv0.w,a_)))); \
          a_ = fmaf(w1.x,hv1.x,fmaf(w1.y,hv1.y,fmaf(w1.z,hv1.z,fmaf(w1.w,hv1.w,a_)))); \
          a_ = fmaf(w2.x,hv2r.x,fmaf(w2.y,hv2r.y,fmaf(w2.z,hv2r.z,fmaf(w2.w,hv2r.w,a_)))); \
          a_ = fmaf(w3.x,hv3.x,fmaf(w3.y,hv3.y,fmaf(w3.z,hv3.z,fmaf(w3.w,hv3.w,a_)))); \
          OUTV = a_; }
      DOTROW(0,v0) DOTROW(1,v1) DOTROW(2,v2) DOTROW(3,v3)
      DOTROW(4,v4) DOTROW(5,v5) DOTROW(6,v6) DOTROW(7,v7)
      #undef DOTROW
    }

    // ---- 10-shuffle folded reduction; lane 8r holds row r ----
    const bool sA = (lane & 32) != 0;
    float a0 = (sA? v4 : v0) + __shfl_xor(sA? v0 : v4, 32, 64);
    float a1 = (sA? v5 : v1) + __shfl_xor(sA? v1 : v5, 32, 64);
    float a2 = (sA? v6 : v2) + __shfl_xor(sA? v2 : v6, 32, 64);
    float a3 = (sA? v7 : v3) + __shfl_xor(sA? v3 : v7, 32, 64);
    const bool sB = (lane & 16) != 0;
    float b0 = (sB? a2 : a0) + __shfl_xor(sB? a0 : a2, 16, 64);
    float b1 = (sB? a3 : a1) + __shfl_xor(sB? a1 : a3, 16, 64);
    const bool sC = (lane & 8) != 0;
    float c0 = (sC? b1 : b0) + __shfl_xor(sC? b0 : b1, 8, 64);
    c0 += __shfl_xor(c0, 4, 64);
    c0 += __shfl_xor(c0, 2, 64);
    c0 += __shfl_xor(c0, 1, 64);

    if (active){
      const float v  = pre_v + c0;
      const float e  = __expf(2.0f * v);
      const float hn = 1.0f - 2.0f / (e + 1.0f);   // tanh(v)
      const size_t d = dbase + myrow;
      if (t != T_STEPS - 1){
        const unsigned long long pkt =
            ((unsigned long long)(unsigned)(t + 1) << 32) |
            (unsigned long long)__float_as_uint(hn);
        const size_t doff = (size_t)((t + 1) & 1)*BD + (size_t)b*DIM + d;
        if constexpr (DUAL){
          // fast copy: workgroup-scope 8B store -> write-through to local L2
          __hip_atomic_store(
              reinterpret_cast<unsigned long long*>(fastbuf + doff),
              pkt, __ATOMIC_RELAXED, __HIP_MEMORY_SCOPE_WORKGROUP);
        }
        // auth copy: LLC (verified r17 path)
        __hip_atomic_store(
            reinterpret_cast<unsigned long long*>(authbuf + doff),
            pkt, __ATOMIC_RELAXED, __HIP_MEMORY_SCOPE_AGENT);
      }
      // validated h + output (cached; read only after kernel end)
      out_h[(size_t)(t+1)*BD + (size_t)b*DIM + d] = hn;
      out  [(size_t)t*BD     + (size_t)b*DIM + d] = hn * gate_v;
    }
  }
}

// ---------------------------------------------------------------------------
extern "C" void kernel_launch(void* const* d_in, const int* in_sizes, int n_in,
                              void* d_out, int out_size, void* d_ws, size_t ws_size,
                              hipStream_t stream){
  (void)in_sizes; (void)n_in; (void)out_size;
  const float* x    = (const float*)d_in[0];
  const float* z    = (const float*)d_in[1];
  const float* h0   = (const float*)d_in[2];
  const float* Wx   = (const float*)d_in[3];
  const float* Wh   = (const float*)d_in[4];
  const float* bias = (const float*)d_in[5];
  float* out   = (float*)d_out;
  float* out_h = out + OUT_SEC;
  uint2* fastbuf = (uint2*)d_ws;
  uint2* authbuf = fastbuf + TAG_UNITS;

  const bool dual = (ws_size >= DUAL_BYTES);
  hipMemsetAsync(d_ws, 0, dual ? DUAL_BYTES : AUTH_BYTES, stream);
  prep_kernel<<<NB_GEMM + NB_GATE, 256, 0, stream>>>(x, Wx, bias, out_h, z, out);
  if (dual)
    rnn_tag<true ><<<256, 512, 0, stream>>>(h0, Wh, out, fastbuf, authbuf);
  else
    rnn_tag<false><<<256, 512, 0, stream>>>(h0, Wh, out, fastbuf, fastbuf);
}

// Round 22
// 1058.653 us; speedup vs baseline: 4.7605x; 4.7605x over previous
//
#include <hip/hip_runtime.h>
#include <math.h>

#define T_STEPS 512
#define BATCH   16
#define DIM     1024
#define M_TOTAL (T_STEPS*BATCH)              // 8192
#define OUT_SEC ((size_t)M_TOTAL*DIM)        // 8388608 floats (output section)
#define BD      (BATCH*DIM)

// ws: two tagged ping-pong exchanges (8B packets, 2 slots x 16 batches x 1024)
//   fast @ 0        : workgroup-scope stores (CU-local; kept only because this
//                     exact build measured 863 us — see r21 post-mortem)
//   auth @ 2*BD u2  : sc0 sc1 stores (LLC, verified r17 protocol)
#define TAG_UNITS   ((size_t)2*BD)
#define AUTH_BYTES  (TAG_UNITS*8)            // 256 KB (fallback minimum)
#define DUAL_BYTES  (TAG_UNITS*8*2)          // 512 KB

// prep grid: 512 GEMM blocks (128x128 tile) + 2048 gate blocks
#define NB_GEMM 512
#define NB_GATE 2048

// ---------------------------------------------------------------------------
__device__ __forceinline__ float wred64(float v){
  #pragma unroll
  for (int off = 32; off >= 1; off >>= 1) v += __shfl_xor(v, off, 64);
  return v;
}

#define KA(v) asm volatile("" : "+v"(v.x), "+v"(v.y), "+v"(v.z), "+v"(v.w))

// ---------------------------------------------------------------------------
// Prep (verified r17/r20, ~196 us): blocks [0,512) = pre GEMM 128x128 tile
// with double-buffered staging; blocks [512,2560) = entmax-1.5 gate.
__global__ __launch_bounds__(256) void prep_kernel(const float* __restrict__ X,
                                                   const float* __restrict__ Wx,
                                                   const float* __restrict__ bias,
                                                   float* __restrict__ out_h,
                                                   const float* __restrict__ z,
                                                   float* __restrict__ gate_out){
  __shared__ float As[8][128];   // k-major A tile (4 KB)
  __shared__ float Bs[8][128];   // k-major B tile (4 KB)
  const int tid = threadIdx.x;

  if (blockIdx.x < NB_GEMM){
    const int bm = blockIdx.x >> 3;
    const int bn = blockIdx.x & 7;
    const int m0 = bm*128, n0 = bn*128;
    const int tx = tid & 15, ty = tid >> 4;
    const int sm = tid >> 1;
    const int sk = (tid & 1) * 4;

    float acc[8][8] = {};

    const float* Xp = X  + (size_t)(m0+sm)*DIM + sk;
    const float* Wp = Wx + (size_t)(n0+sm)*DIM + sk;

    float4 av = *reinterpret_cast<const float4*>(Xp);
    float4 wv = *reinterpret_cast<const float4*>(Wp);

    for (int k0 = 0; k0 < DIM; k0 += 8){
      __syncthreads();                  // previous compute done reading LDS
      As[sk+0][sm]=av.x; As[sk+1][sm]=av.y; As[sk+2][sm]=av.z; As[sk+3][sm]=av.w;
      Bs[sk+0][sm]=wv.x; Bs[sk+1][sm]=wv.y; Bs[sk+2][sm]=wv.z; Bs[sk+3][sm]=wv.w;
      const int kn = (k0 + 8 < DIM) ? (k0 + 8) : 0;
      const float4 av2 = *reinterpret_cast<const float4*>(Xp + kn);
      const float4 wv2 = *reinterpret_cast<const float4*>(Wp + kn);
      __syncthreads();
      #pragma unroll
      for (int k = 0; k < 8; ++k){
        float af[8], bf[8];
        #pragma unroll
        for (int i = 0; i < 8; ++i) af[i] = As[k][ty + 16*i];
        #pragma unroll
        for (int j = 0; j < 8; ++j) bf[j] = Bs[k][tx + 16*j];
        #pragma unroll
        for (int i = 0; i < 8; ++i)
          #pragma unroll
          for (int j = 0; j < 8; ++j) acc[i][j] = fmaf(af[i], bf[j], acc[i][j]);
      }
      av = av2; wv = wv2;
    }

    float bv[8];
    #pragma unroll
    for (int j = 0; j < 8; ++j) bv[j] = bias[n0 + tx + 16*j];
    #pragma unroll
    for (int i = 0; i < 8; ++i){
      float* dst = out_h + (size_t)(m0 + ty + 16*i + BATCH)*DIM + n0 + tx;
      #pragma unroll
      for (int j = 0; j < 8; ++j) dst[16*j] = acc[i][j] + bv[j];
    }
  } else {
    const int gb   = blockIdx.x - NB_GEMM;
    const int row  = gb * 4 + (tid >> 6);
    const int lane = tid & 63;
    const float* zr = z + (size_t)row * DIM;

    float x[16];
    #pragma unroll
    for (int e = 0; e < 4; ++e){
      float4 v = *reinterpret_cast<const float4*>(zr + e*256 + lane*4);
      x[e*4+0]=v.x; x[e*4+1]=v.y; x[e*4+2]=v.z; x[e*4+3]=v.w;
    }

    float m = x[0];
    #pragma unroll
    for (int i = 1; i < 16; ++i) m = fmaxf(m, x[i]);
    #pragma unroll
    for (int off = 32; off >= 1; off >>= 1) m = fmaxf(m, __shfl_xor(m, off, 64));

    float lo = m - 1.0f, hi = m;
    for (int it = 0; it < 30; ++it){
      float mid = 0.5f*(lo + hi);
      float f = 0.f;
      #pragma unroll
      for (int i = 0; i < 16; ++i) f += fmaxf(x[i] - mid, 0.f);
      f = wred64(f);
      if (f >= 1.0f) lo = mid; else hi = mid;
    }
    float s = 0.f, kc = 0.f;
    #pragma unroll
    for (int i = 0; i < 16; ++i){ if (x[i] > lo){ s += x[i]; kc += 1.f; } }
    s = wred64(s); kc = wred64(kc);
    const float tau = (s - 1.0f) / kc;

    float p[16]; float ps = 0.f;
    #pragma unroll
    for (int i = 0; i < 16; ++i){ p[i] = sqrtf(fmaxf(x[i] - tau, 0.f)); ps += p[i]; }
    ps = wred64(ps);
    const float inv = 1.0f / (ps + 1e-10f);

    float* go = gate_out + (size_t)row * DIM;
    #pragma unroll
    for (int e = 0; e < 4; ++e){
      float4 v; v.x=p[e*4]*inv; v.y=p[e*4+1]*inv; v.z=p[e*4+2]*inv; v.w=p[e*4+3]*inv;
      *reinterpret_cast<float4*>(go + e*256 + lane*4) = v;
    }
  }
}

// ---------------------------------------------------------------------------
// Kernel C: r20 build (verified 863 us) — dual-path exchange, poll waits
// vmcnt(0) on both loads and accepts whichever copy shows tag t. r21 proved
// the fast (workgroup-scope) copy never detects cross-CU; the auth (LLC)
// copy is the real carrier. This exact structure is the best measured.
template<bool DUAL>
__global__ __launch_bounds__(512, 1) void rnn_tag(const float* __restrict__ h0,
                                                  const float* __restrict__ Wh,
                                                  float* __restrict__ out,
                                                  uint2* __restrict__ fastbuf,
                                                  uint2* __restrict__ authbuf){
  float* out_h = out + OUT_SEC;
  const int tid  = threadIdx.x;
  const int lane = tid & 63;
  const int w    = tid >> 6;            // wave 0..7
  const int b    = blockIdx.x & 15;     // batch (XCD-affine under round-robin)
  const int s    = blockIdx.x >> 4;     // slice
  const int dbase = s*64 + w*8;

  __shared__ float hbuf[2][DIM];        // 8 KB ping-pong broadcast buffer

  // W_h slice: 8 rows x 16 cols = 32 float4
  float4 wreg[8][4];
  #pragma unroll
  for (int r = 0; r < 8; ++r)
    #pragma unroll
    for (int j = 0; j < 4; ++j)
      wreg[r][j] = *reinterpret_cast<const float4*>(
          Wh + (size_t)(dbase + r)*DIM + lane*4 + j*256);

  KA(wreg[0][0]); KA(wreg[0][1]); KA(wreg[0][2]); KA(wreg[0][3]);
  KA(wreg[1][0]); KA(wreg[1][1]); KA(wreg[1][2]); KA(wreg[1][3]);
  KA(wreg[2][0]); KA(wreg[2][1]); KA(wreg[2][2]); KA(wreg[2][3]);
  KA(wreg[3][0]); KA(wreg[3][1]); KA(wreg[3][2]); KA(wreg[3][3]);
  KA(wreg[4][0]); KA(wreg[4][1]); KA(wreg[4][2]); KA(wreg[4][3]);
  KA(wreg[5][0]); KA(wreg[5][1]); KA(wreg[5][2]); KA(wreg[5][3]);
  KA(wreg[6][0]); KA(wreg[6][1]); KA(wreg[6][2]); KA(wreg[6][3]);
  KA(wreg[7][0]); KA(wreg[7][1]); KA(wreg[7][2]); KA(wreg[7][3]);

  // h[0] = h0 in the validated h section (output slot 0)
  if (tid < 16)
    reinterpret_cast<float4*>(out_h + (size_t)b*DIM + s*64)[tid] =
        reinterpret_cast<const float4*>(h0 + (size_t)b*DIM + s*64)[tid];

  const int myrow   = lane >> 3;            // 0..7
  const bool active = ((lane & 7) == 0);    // 8 store lanes per wave

  for (int t = 0; t < T_STEPS; ++t){
    // prefetch pre (h slot t+1) and gate (out slot t) for this lane's row
    float pre_v = 0.f, gate_v = 0.f;
    if (active){
      const size_t d = dbase + myrow;
      pre_v  = out_h[(size_t)(t+1)*BD + (size_t)b*DIM + d];
      gate_v = out  [(size_t)t*BD     + (size_t)b*DIM + d];
    }

    // ---- acquire h[t][b] into LDS (distributed poll, 2 packets/thread) ----
    if (t == 0){
      const float2 hl = *reinterpret_cast<const float2*>(h0 + (size_t)b*DIM + 2*tid);
      *reinterpret_cast<float2*>(&hbuf[0][2*tid]) = hl;
    } else {
      const size_t off = (size_t)(t & 1)*BD + (size_t)b*DIM + 2*tid;
      const unsigned want = (unsigned)t;
      if constexpr (DUAL){
        const uint2* pf = fastbuf + off;
        const uint2* pa = authbuf + off;
        float4 f, a;
        for (;;){
          asm volatile("global_load_dwordx4 %0, %2, off sc0\n\t"
                       "global_load_dwordx4 %1, %3, off sc0 sc1\n\t"
                       "s_waitcnt vmcnt(0)"
                       : "=&v"(f), "=&v"(a) : "v"(pf), "v"(pa) : "memory");
          const bool ok0 = (__float_as_uint(f.y)==want) | (__float_as_uint(a.y)==want);
          const bool ok1 = (__float_as_uint(f.w)==want) | (__float_as_uint(a.w)==want);
          if (ok0 & ok1) break;
        }
        const float v0 = (__float_as_uint(f.y)==want) ? f.x : a.x;
        const float v1 = (__float_as_uint(f.w)==want) ? f.z : a.z;
        *reinterpret_cast<float2*>(&hbuf[t & 1][2*tid]) = make_float2(v0, v1);
      } else {
        const uint2* pp = authbuf + off;
        float4 q;
        do {
          asm volatile("global_load_dwordx4 %0, %1, off sc0 sc1\n\t"
                       "s_waitcnt vmcnt(0)"
                       : "=&v"(q) : "v"(pp) : "memory");
        } while (__float_as_uint(q.y) != want || __float_as_uint(q.w) != want);
        *reinterpret_cast<float2*>(&hbuf[t & 1][2*tid]) = make_float2(q.x, q.z);
      }
    }
    __syncthreads();

    const float* src = &hbuf[t & 1][0];
    const float4 hv0 = *reinterpret_cast<const float4*>(src + lane*4);
    const float4 hv1 = *reinterpret_cast<const float4*>(src + 256 + lane*4);
    const float4 hv2 = *reinterpret_cast<const float4*>(src + 512 + lane*4);
    const float4 hv3 = *reinterpret_cast<const float4*>(src + 768 + lane*4);

    // ---- partials: v[r] = dot(wreg[r], hv) over this lane's 16 cols ----
    float v0,v1,v2,v3,v4,v5,v6,v7;
    {
      #define DOTROW(R, OUTV)                                            \
        { const float4 w0=wreg[R][0], w1=wreg[R][1],                     \
                       w2=wreg[R][2], w3=wreg[R][3];                     \
          float a_ = 0.f;                                                \
          a_ = fmaf(w0.x,hv0.x,fmaf(w0.y,hv0.y,fmaf(w0.z,hv0.z,fmaf(w0.w,hv0.w,a_)))); \
          a_ = fmaf(w1.x,hv1.x,fmaf(w1.y,hv1.y,fmaf(w1.z,hv1.z,fmaf(w1.w,hv1.w,a_)))); \
          a_ = fmaf(w2.x,hv2.x,fmaf(w2.y,hv2.y,fmaf(w2.z,hv2.z,fmaf(w2.w,hv2.w,a_)))); \
          a_ = fmaf(w3.x,hv3.x,fmaf(w3.y,hv3.y,fmaf(w3.z,hv3.z,fmaf(w3.w,hv3.w,a_)))); \
          OUTV = a_; }
      DOTROW(0,v0) DOTROW(1,v1) DOTROW(2,v2) DOTROW(3,v3)
      DOTROW(4,v4) DOTROW(5,v5) DOTROW(6,v6) DOTROW(7,v7)
      #undef DOTROW
    }

    // ---- 10-shuffle folded reduction; lane 8r holds row r ----
    const bool sA = (lane & 32) != 0;
    float a0 = (sA? v4 : v0) + __shfl_xor(sA? v0 : v4, 32, 64);
    float a1 = (sA? v5 : v1) + __shfl_xor(sA? v1 : v5, 32, 64);
    float a2 = (sA? v6 : v2) + __shfl_xor(sA? v2 : v6, 32, 64);
    float a3 = (sA? v7 : v3) + __shfl_xor(sA? v3 : v7, 32, 64);
    const bool sB = (lane & 16) != 0;
    float b0 = (sB? a2 : a0) + __shfl_xor(sB? a0 : a2, 16, 64);
    float b1 = (sB? a3 : a1) + __shfl_xor(sB? a1 : a3, 16, 64);
    const bool sC = (lane & 8) != 0;
    float c0 = (sC? b1 : b0) + __shfl_xor(sC? b0 : b1, 8, 64);
    c0 += __shfl_xor(c0, 4, 64);
    c0 += __shfl_xor(c0, 2, 64);
    c0 += __shfl_xor(c0, 1, 64);

    if (active){
      const float v  = pre_v + c0;
      const float e  = __expf(2.0f * v);
      const float hn = 1.0f - 2.0f / (e + 1.0f);   // tanh(v)
      const size_t d = dbase + myrow;
      if (t != T_STEPS - 1){
        const unsigned long long pkt =
            ((unsigned long long)(unsigned)(t + 1) << 32) |
            (unsigned long long)__float_as_uint(hn);
        const size_t doff = (size_t)((t + 1) & 1)*BD + (size_t)b*DIM + d;
        if constexpr (DUAL){
          __hip_atomic_store(
              reinterpret_cast<unsigned long long*>(fastbuf + doff),
              pkt, __ATOMIC_RELAXED, __HIP_MEMORY_SCOPE_WORKGROUP);
        }
        __hip_atomic_store(
            reinterpret_cast<unsigned long long*>(authbuf + doff),
            pkt, __ATOMIC_RELAXED, __HIP_MEMORY_SCOPE_AGENT);
      }
      // validated h + output (cached; read only after kernel end)
      out_h[(size_t)(t+1)*BD + (size_t)b*DIM + d] = hn;
      out  [(size_t)t*BD     + (size_t)b*DIM + d] = hn * gate_v;
    }
  }
}

// ---------------------------------------------------------------------------
extern "C" void kernel_launch(void* const* d_in, const int* in_sizes, int n_in,
                              void* d_out, int out_size, void* d_ws, size_t ws_size,
                              hipStream_t stream){
  (void)in_sizes; (void)n_in; (void)out_size;
  const float* x    = (const float*)d_in[0];
  const float* z    = (const float*)d_in[1];
  const float* h0   = (const float*)d_in[2];
  const float* Wx   = (const float*)d_in[3];
  const float* Wh   = (const float*)d_in[4];
  const float* bias = (const float*)d_in[5];
  float* out   = (float*)d_out;
  float* out_h = out + OUT_SEC;
  uint2* fastbuf = (uint2*)d_ws;
  uint2* authbuf = fastbuf + TAG_UNITS;

  const bool dual = (ws_size >= DUAL_BYTES);
  hipMemsetAsync(d_ws, 0, dual ? DUAL_BYTES : AUTH_BYTES, stream);
  prep_kernel<<<NB_GEMM + NB_GATE, 256, 0, stream>>>(x, Wx, bias, out_h, z, out);
  if (dual)
    rnn_tag<true ><<<256, 512, 0, stream>>>(h0, Wh, out, fastbuf, authbuf);
  else
    rnn_tag<false><<<256, 512, 0, stream>>>(h0, Wh, out, fastbuf, fastbuf);
}